// Round 2
// baseline (718.291 us; speedup 1.0000x reference)
//
#include <hip/hip_runtime.h>
#include <math.h>

// ---------------------------------------------------------------------------
// HDRL Poincare MLR, c=1.
//   out[b,o] = asinh( 2*sc / (|Bc*(1-x2)/Dd| * an + 1e-15) ) * an
//   sc = (Bc*xa - A*pa)/Dd,  A = 1-2px+x2, Dd = 1-2px+p2*x2, Bc = 1-p2
// px = <x_b, p_o>, xa = <x_b, a_o> via dual bf16 MFMA GEMM (shared x tiles).
// Stable identity: 1 - |mobius_add(-p,x)|^2 = Bc*(1-x2)/Dd  (no cancellation).
//
// R2: T2 LDS XOR-swizzle (st-16B chunks) via pre-swizzled global source
//     (global_load_lds writes linearly — rule #21), swizzled ds_read;
//     occupancy 2->3 blocks/CU.
// ---------------------------------------------------------------------------

#define B_DIM 8192
#define O_DIM 4096
#define K_DIM 1024

using f32x4  = __attribute__((ext_vector_type(4))) float;
using bf16x8 = __attribute__((ext_vector_type(8))) short;

__device__ inline unsigned short f2bf(float f) {
  union { float f; unsigned u; } v; v.f = f;
  unsigned u = v.u;
  u += 0x7FFFu + ((u >> 16) & 1u);   // RNE
  return (unsigned short)(u >> 16);
}

__device__ inline void load_lds16(const void* g, void* l) {
  __builtin_amdgcn_global_load_lds(
      (const __attribute__((address_space(1))) void*)g,
      (__attribute__((address_space(3))) void*)l, 16, 0, 0);
}

// ---- per-output-row stats + bf16 conversion (weight & projected bias) -----
__global__ __launch_bounds__(256) void prep_rows(
    const float* __restrict__ wgt, const float* __restrict__ bia,
    unsigned short* __restrict__ a_bf, unsigned short* __restrict__ p_bf,
    float* __restrict__ p2v, float* __restrict__ pav, float* __restrict__ anv)
{
  const int o = blockIdx.x, t = threadIdx.x;
  const float4 w = ((const float4*)(wgt + (size_t)o * K_DIM))[t];
  const float4 b = ((const float4*)(bia + (size_t)o * K_DIM))[t];
  float a2 = w.x*w.x + w.y*w.y + w.z*w.z + w.w*w.w;
  float b2 = b.x*b.x + b.y*b.y + b.z*b.z + b.w*b.w;
  float ab = w.x*b.x + w.y*b.y + w.z*b.z + w.w*b.w;
  #pragma unroll
  for (int off = 32; off; off >>= 1) {
    a2 += __shfl_down(a2, off);
    b2 += __shfl_down(b2, off);
    ab += __shfl_down(ab, off);
  }
  __shared__ float sa[4], sb[4], sc_[4];
  const int wv = t >> 6, ln = t & 63;
  if (ln == 0) { sa[wv] = a2; sb[wv] = b2; sc_[wv] = ab; }
  __syncthreads();
  const float A2 = sa[0] + sa[1] + sa[2] + sa[3];
  const float B2 = sb[0] + sb[1] + sb[2] + sb[3];
  const float AB = sc_[0] + sc_[1] + sc_[2] + sc_[3];
  const float norm = sqrtf(B2);
  const float maxn = 1.0f - 1e-5f;            // (1-PROJ_EPS)/sqrt(c), c=1
  const float s = (norm > maxn) ? (maxn / norm) : 1.0f;
  if (t == 0) { p2v[o] = B2 * s * s; pav[o] = AB * s; anv[o] = sqrtf(A2); }
  unsigned short* ao = a_bf + (size_t)o * K_DIM + t * 4;
  unsigned short* po = p_bf + (size_t)o * K_DIM + t * 4;
  ao[0] = f2bf(w.x); ao[1] = f2bf(w.y); ao[2] = f2bf(w.z); ao[3] = f2bf(w.w);
  po[0] = f2bf(b.x * s); po[1] = f2bf(b.y * s); po[2] = f2bf(b.z * s); po[3] = f2bf(b.w * s);
}

// ---- per-batch-row stats + bf16 conversion of x ---------------------------
__global__ __launch_bounds__(256) void prep_x(
    const float* __restrict__ x, unsigned short* __restrict__ x_bf,
    float* __restrict__ x2v)
{
  const int bi = blockIdx.x, t = threadIdx.x;
  const float4 v = ((const float4*)(x + (size_t)bi * K_DIM))[t];
  float s2 = v.x*v.x + v.y*v.y + v.z*v.z + v.w*v.w;
  #pragma unroll
  for (int off = 32; off; off >>= 1) s2 += __shfl_down(s2, off);
  __shared__ float sl[4];
  const int wv = t >> 6, ln = t & 63;
  if (ln == 0) sl[wv] = s2;
  __syncthreads();
  if (t == 0) x2v[bi] = sl[0] + sl[1] + sl[2] + sl[3];
  unsigned short* xo = x_bf + (size_t)bi * K_DIM + t * 4;
  xo[0] = f2bf(v.x); xo[1] = f2bf(v.y); xo[2] = f2bf(v.z); xo[3] = f2bf(v.w);
}

// ---- main dual-GEMM + fused epilogue ---------------------------------------
// 128x128 tile, BK=64, 4 waves (each owns a 64x64 quadrant, 4x4 MFMA frags
// per output). global_load_lds width-16 staging, linear LDS dest with
// inverse-swizzled global source; ds_read uses the matching XOR swizzle.
__global__ __launch_bounds__(256, 3) void hdrl_main(
    const unsigned short* __restrict__ Xb,
    const unsigned short* __restrict__ Pb,
    const unsigned short* __restrict__ Ab,
    const float* __restrict__ x2v, const float* __restrict__ p2v,
    const float* __restrict__ pav, const float* __restrict__ anv,
    float* __restrict__ out)
{
  __shared__ unsigned short As[128 * 64];
  __shared__ unsigned short Ps[128 * 64];
  __shared__ unsigned short Ws[128 * 64];

  const int bid  = blockIdx.x;
  const int mt   = bid % (B_DIM / 128);       // 64 m-tiles
  const int nt   = bid / (B_DIM / 128);       // 32 n-tiles
  const int row0 = mt * 128, col0 = nt * 128;
  const int t    = threadIdx.x;
  const int wv   = t >> 6, lane = t & 63;
  const int wr   = (wv >> 1) * 64, wc = (wv & 1) * 64;
  const int lrow = lane & 15, kg = lane >> 4;

  f32x4 accp[4][4], acca[4][4];
  #pragma unroll
  for (int i = 0; i < 4; ++i)
    #pragma unroll
    for (int j = 0; j < 4; ++j) { accp[i][j] = (f32x4)0.0f; acca[i][j] = (f32x4)0.0f; }

  const int srow = lane >> 3;                    // row within 8-row chunk
  const int scol = ((lane & 7) ^ srow) * 8;      // inverse-swizzled source col

  for (int kt = 0; kt < K_DIM / 64; ++kt) {
    const int k0 = kt * 64;
    #pragma unroll
    for (int q = 0; q < 4; ++q) {
      const int chunk = q * 4 + wv;                 // 0..15, wave-uniform
      const int r     = chunk * 8 + srow;           // 0..127
      const size_t ga = (size_t)(row0 + r) * K_DIM + k0 + scol;
      const size_t gb = (size_t)(col0 + r) * K_DIM + k0 + scol;
      const int    lo = chunk * 512;                // elements (1 KB chunks)
      load_lds16(Xb + ga, (void*)(As + lo));
      load_lds16(Pb + gb, (void*)(Ps + lo));
      load_lds16(Ab + gb, (void*)(Ws + lo));
    }
    __syncthreads();
    #pragma unroll
    for (int kk = 0; kk < 2; ++kk) {
      const int kb  = kk * 32 + kg * 8;
      const int kbs = kb ^ ((lrow & 7) << 3);      // swizzled read col
      bf16x8 af[4], pf[4], wf[4];
      #pragma unroll
      for (int i = 0; i < 4; ++i)
        af[i] = *(const bf16x8*)&As[(wr + i * 16 + lrow) * 64 + kbs];
      #pragma unroll
      for (int j = 0; j < 4; ++j) {
        pf[j] = *(const bf16x8*)&Ps[(wc + j * 16 + lrow) * 64 + kbs];
        wf[j] = *(const bf16x8*)&Ws[(wc + j * 16 + lrow) * 64 + kbs];
      }
      #pragma unroll
      for (int i = 0; i < 4; ++i)
        #pragma unroll
        for (int j = 0; j < 4; ++j) {
          accp[i][j] = __builtin_amdgcn_mfma_f32_16x16x32_bf16(af[i], pf[j], accp[i][j], 0, 0, 0);
          acca[i][j] = __builtin_amdgcn_mfma_f32_16x16x32_bf16(af[i], wf[j], acca[i][j], 0, 0, 0);
        }
    }
    __syncthreads();
  }

  // fused epilogue: C/D layout col = lane&15, row = (lane>>4)*4 + reg
  #pragma unroll
  for (int j = 0; j < 4; ++j) {
    const int col = col0 + wc + j * 16 + lrow;
    const float p2 = p2v[col], pa = pav[col], an = anv[col];
    const float Bc = 1.0f - p2;
    #pragma unroll
    for (int i = 0; i < 4; ++i) {
      const int rbase = row0 + wr + i * 16 + kg * 4;
      #pragma unroll
      for (int r = 0; r < 4; ++r) {
        const int row = rbase + r;
        const float x2 = x2v[row];
        const float px = accp[i][j][r];
        const float xa = acca[i][j][r];
        const float Aq = 1.0f - 2.0f * px + x2;
        const float Dd = 1.0f - 2.0f * px + p2 * x2;
        const float inv = 1.0f / Dd;
        const float sc = (Bc * xa - Aq * pa) * inv;
        const float dnm = fabsf(Bc * (1.0f - x2) * inv) * an + 1e-15f;
        out[(size_t)row * O_DIM + col] = asinhf(2.0f * sc / dnm) * an;
      }
    }
  }
}

extern "C" void kernel_launch(void* const* d_in, const int* in_sizes, int n_in,
                              void* d_out, int out_size, void* d_ws, size_t ws_size,
                              hipStream_t stream) {
  (void)in_sizes; (void)n_in; (void)out_size; (void)ws_size;
  const float* x = (const float*)d_in[0];
  const float* w = (const float*)d_in[1];
  const float* b = (const float*)d_in[2];
  float* out = (float*)d_out;

  char* ws = (char*)d_ws;
  unsigned short* x_bf = (unsigned short*)ws;                               // 16 MB
  unsigned short* p_bf = (unsigned short*)(ws + (size_t)16 * 1024 * 1024);  //  8 MB
  unsigned short* a_bf = (unsigned short*)(ws + (size_t)24 * 1024 * 1024);  //  8 MB
  float* p2v = (float*)(ws + (size_t)32 * 1024 * 1024);
  float* pav = p2v + O_DIM;
  float* anv = pav + O_DIM;
  float* x2v = anv + O_DIM;

  prep_rows<<<O_DIM, 256, 0, stream>>>(w, b, a_bf, p_bf, p2v, pav, anv);
  prep_x<<<B_DIM, 256, 0, stream>>>(x, x_bf, x2v);

  const int grid = (B_DIM / 128) * (O_DIM / 128);   // 2048
  hdrl_main<<<grid, 256, 0, stream>>>(x_bf, p_bf, a_bf, x2v, p2v, pav, anv, out);
}

// Round 3
// 284.357 us; speedup vs baseline: 2.5260x; 2.5260x over previous
//
#include <hip/hip_runtime.h>
#include <math.h>

// ---------------------------------------------------------------------------
// HDRL Poincare MLR, c=1.
//   out[b,o] = asinh( 2*sc / (|Bc*(1-x2)/Dd| * an + 1e-15) ) * an
//   sc = (Bc*xa - A*pa)/Dd,  A = 1-2px+x2, Dd = 1-2px+p2*x2, Bc = 1-p2
// px = <x_b, p_o>, xa = <x_b, a_o> via dual bf16 MFMA GEMM (shared x tiles).
//
// R3: 8-wave 256x128-dual tile, 4-phase/K-tile deep schedule (T3-style),
//     double-buffered 128KB LDS, XOR chunk swizzle (T2), setprio (T5).
//     Tile-boundary __syncthreads() (full drain) for race safety.
// ---------------------------------------------------------------------------

#define B_DIM 8192
#define O_DIM 4096
#define K_DIM 1024

using f32x4  = __attribute__((ext_vector_type(4))) float;
using bf16x8 = __attribute__((ext_vector_type(8))) short;

__device__ inline unsigned short f2bf(float f) {
  union { float f; unsigned u; } v; v.f = f;
  unsigned u = v.u;
  u += 0x7FFFu + ((u >> 16) & 1u);   // RNE
  return (unsigned short)(u >> 16);
}

__device__ inline void load_lds16(const void* g, void* l) {
  __builtin_amdgcn_global_load_lds(
      (const __attribute__((address_space(1))) void*)g,
      (__attribute__((address_space(3))) void*)l, 16, 0, 0);
}

// ---- per-output-row stats + bf16 conversion (weight & projected bias) -----
__global__ __launch_bounds__(256) void prep_rows(
    const float* __restrict__ wgt, const float* __restrict__ bia,
    unsigned short* __restrict__ a_bf, unsigned short* __restrict__ p_bf,
    float* __restrict__ p2v, float* __restrict__ pav, float* __restrict__ anv)
{
  const int o = blockIdx.x, t = threadIdx.x;
  const float4 w = ((const float4*)(wgt + (size_t)o * K_DIM))[t];
  const float4 b = ((const float4*)(bia + (size_t)o * K_DIM))[t];
  float a2 = w.x*w.x + w.y*w.y + w.z*w.z + w.w*w.w;
  float b2 = b.x*b.x + b.y*b.y + b.z*b.z + b.w*b.w;
  float ab = w.x*b.x + w.y*b.y + w.z*b.z + w.w*b.w;
  #pragma unroll
  for (int off = 32; off; off >>= 1) {
    a2 += __shfl_down(a2, off);
    b2 += __shfl_down(b2, off);
    ab += __shfl_down(ab, off);
  }
  __shared__ float sa[4], sb[4], sc_[4];
  const int wv = t >> 6, ln = t & 63;
  if (ln == 0) { sa[wv] = a2; sb[wv] = b2; sc_[wv] = ab; }
  __syncthreads();
  const float A2 = sa[0] + sa[1] + sa[2] + sa[3];
  const float B2 = sb[0] + sb[1] + sb[2] + sb[3];
  const float AB = sc_[0] + sc_[1] + sc_[2] + sc_[3];
  const float norm = sqrtf(B2);
  const float maxn = 1.0f - 1e-5f;            // (1-PROJ_EPS)/sqrt(c), c=1
  const float s = (norm > maxn) ? (maxn / norm) : 1.0f;
  if (t == 0) { p2v[o] = B2 * s * s; pav[o] = AB * s; anv[o] = sqrtf(A2); }
  unsigned short* ao = a_bf + (size_t)o * K_DIM + t * 4;
  unsigned short* po = p_bf + (size_t)o * K_DIM + t * 4;
  ao[0] = f2bf(w.x); ao[1] = f2bf(w.y); ao[2] = f2bf(w.z); ao[3] = f2bf(w.w);
  po[0] = f2bf(b.x * s); po[1] = f2bf(b.y * s); po[2] = f2bf(b.z * s); po[3] = f2bf(b.w * s);
}

// ---- per-batch-row stats + bf16 conversion of x ---------------------------
__global__ __launch_bounds__(256) void prep_x(
    const float* __restrict__ x, unsigned short* __restrict__ x_bf,
    float* __restrict__ x2v)
{
  const int bi = blockIdx.x, t = threadIdx.x;
  const float4 v = ((const float4*)(x + (size_t)bi * K_DIM))[t];
  float s2 = v.x*v.x + v.y*v.y + v.z*v.z + v.w*v.w;
  #pragma unroll
  for (int off = 32; off; off >>= 1) s2 += __shfl_down(s2, off);
  __shared__ float sl[4];
  const int wv = t >> 6, ln = t & 63;
  if (ln == 0) sl[wv] = s2;
  __syncthreads();
  if (t == 0) x2v[bi] = sl[0] + sl[1] + sl[2] + sl[3];
  unsigned short* xo = x_bf + (size_t)bi * K_DIM + t * 4;
  xo[0] = f2bf(v.x); xo[1] = f2bf(v.y); xo[2] = f2bf(v.z); xo[3] = f2bf(v.w);
}

// ---- main dual-GEMM + fused epilogue ---------------------------------------
// 8 waves (4M x 2N). BM=256, BN=128 (dual P/W), BK=64. 16 K-tiles.
// LDS per buffer (bf16 elems): A[256*64]=16384 @0, P[128*64]=8192 @16384,
// W[128*64]=8192 @24576; buffer stride 32768 elems; 2 buffers = 128 KB.
__global__ __launch_bounds__(512, 2) void hdrl_main(
    const unsigned short* __restrict__ Xb,
    const unsigned short* __restrict__ Pb,
    const unsigned short* __restrict__ Ab,
    const float* __restrict__ x2v, const float* __restrict__ p2v,
    const float* __restrict__ pav, const float* __restrict__ anv,
    float* __restrict__ out)
{
  extern __shared__ unsigned short lds[];

  const int bid  = blockIdx.x;
  const int mt   = bid & 31;                  // 32 m-tiles (256 rows)
  const int nt   = bid >> 5;                  // 32 n-tiles (128 cols)
  const int row0 = mt * 256, col0 = nt * 128;
  const int t    = threadIdx.x;
  const int wv   = t >> 6, lane = t & 63;
  const int wm   = wv >> 1, wn = wv & 1;      // 4M x 2N waves
  const int lrow = lane & 15, kg = lane >> 4;
  const int sw   = (lrow & 7) << 3;           // read-side XOR key (elems)

  // staging: thread t covers chunk (r = q*64 + (t>>3), c = t&7), 16B chunks
  const int sr   = t >> 3;                    // 0..63
  const int sc   = t & 7;
  const int scol = (sc ^ (sr & 7)) * 8;       // inverse-swizzled source col
  const unsigned short* gA = Xb + (size_t)(row0 + sr) * K_DIM + scol;
  const unsigned short* gP = Pb + (size_t)(col0 + sr) * K_DIM + scol;
  const unsigned short* gW = Ab + (size_t)(col0 + sr) * K_DIM + scol;

  f32x4 accp[4][4], acca[4][4];
  #pragma unroll
  for (int i = 0; i < 4; ++i)
    #pragma unroll
    for (int j = 0; j < 4; ++j) { accp[i][j] = (f32x4)0.0f; acca[i][j] = (f32x4)0.0f; }

#define STAGE_A(q) load_lds16(gA + (size_t)(q)*64*K_DIM + k0n, (void*)&lds[nb + (q)*4096 + wv*512])
#define STAGE_P(q) load_lds16(gP + (size_t)(q)*64*K_DIM + k0n, (void*)&lds[nb + 16384 + (q)*4096 + wv*512])
#define STAGE_W(q) load_lds16(gW + (size_t)(q)*64*K_DIM + k0n, (void*)&lds[nb + 24576 + (q)*4096 + wv*512])

  // prologue: stage tile 0 into buffer 0
  {
    const int nb = 0, k0n = 0;
    STAGE_A(0); STAGE_A(1); STAGE_A(2); STAGE_A(3);
    STAGE_P(0); STAGE_P(1); STAGE_W(0); STAGE_W(1);
  }
  __syncthreads();

  int cur = 0;
  for (int kt = 0; kt < 16; ++kt) {
    const int nxt = cur ^ 1;
    const int nb  = nxt * 32768;
    const int cb  = cur * 32768;
    const int k0n = (kt + 1) * 64;
    const bool pfn = (kt < 15);

    bf16x8 af[4][2], bg[4][2];
    const int kbs0 = (kg * 8) ^ sw;
    const int kbs1 = (32 + kg * 8) ^ sw;

    // ---- phase 0: read af[0..1], all P frags; stage A0,A1,P0 --------------
    #pragma unroll
    for (int i = 0; i < 2; ++i) {
      af[i][0] = *(const bf16x8*)&lds[cb + (wm*64 + i*16 + lrow)*64 + kbs0];
      af[i][1] = *(const bf16x8*)&lds[cb + (wm*64 + i*16 + lrow)*64 + kbs1];
    }
    #pragma unroll
    for (int j = 0; j < 4; ++j) {
      bg[j][0] = *(const bf16x8*)&lds[cb + 16384 + (wn*64 + j*16 + lrow)*64 + kbs0];
      bg[j][1] = *(const bf16x8*)&lds[cb + 16384 + (wn*64 + j*16 + lrow)*64 + kbs1];
    }
    if (pfn) { STAGE_A(0); STAGE_A(1); STAGE_P(0); }
    __builtin_amdgcn_s_barrier();
    asm volatile("s_waitcnt lgkmcnt(0)" ::: "memory");
    __builtin_amdgcn_s_setprio(1);
    #pragma unroll
    for (int i = 0; i < 2; ++i)
      #pragma unroll
      for (int j = 0; j < 4; ++j)
        #pragma unroll
        for (int kk = 0; kk < 2; ++kk)
          accp[i][j] = __builtin_amdgcn_mfma_f32_16x16x32_bf16(af[i][kk], bg[j][kk], accp[i][j], 0, 0, 0);
    __builtin_amdgcn_s_setprio(0);
    __builtin_amdgcn_s_barrier();

    // ---- phase 1: read af[2..3]; stage A2,A3,P1 ---------------------------
    #pragma unroll
    for (int i = 2; i < 4; ++i) {
      af[i][0] = *(const bf16x8*)&lds[cb + (wm*64 + i*16 + lrow)*64 + kbs0];
      af[i][1] = *(const bf16x8*)&lds[cb + (wm*64 + i*16 + lrow)*64 + kbs1];
    }
    if (pfn) { STAGE_A(2); STAGE_A(3); STAGE_P(1); }
    __builtin_amdgcn_s_barrier();
    asm volatile("s_waitcnt lgkmcnt(0)" ::: "memory");
    __builtin_amdgcn_s_setprio(1);
    #pragma unroll
    for (int i = 2; i < 4; ++i)
      #pragma unroll
      for (int j = 0; j < 4; ++j)
        #pragma unroll
        for (int kk = 0; kk < 2; ++kk)
          accp[i][j] = __builtin_amdgcn_mfma_f32_16x16x32_bf16(af[i][kk], bg[j][kk], accp[i][j], 0, 0, 0);
    __builtin_amdgcn_s_setprio(0);
    __builtin_amdgcn_s_barrier();

    // ---- phase 2: read all W frags (reuse bg); stage W0,W1 ----------------
    #pragma unroll
    for (int j = 0; j < 4; ++j) {
      bg[j][0] = *(const bf16x8*)&lds[cb + 24576 + (wn*64 + j*16 + lrow)*64 + kbs0];
      bg[j][1] = *(const bf16x8*)&lds[cb + 24576 + (wn*64 + j*16 + lrow)*64 + kbs1];
    }
    if (pfn) { STAGE_W(0); STAGE_W(1); }
    __builtin_amdgcn_s_barrier();
    asm volatile("s_waitcnt lgkmcnt(0)" ::: "memory");
    __builtin_amdgcn_s_setprio(1);
    #pragma unroll
    for (int i = 0; i < 2; ++i)
      #pragma unroll
      for (int j = 0; j < 4; ++j)
        #pragma unroll
        for (int kk = 0; kk < 2; ++kk)
          acca[i][j] = __builtin_amdgcn_mfma_f32_16x16x32_bf16(af[i][kk], bg[j][kk], acca[i][j], 0, 0, 0);
    __builtin_amdgcn_s_setprio(0);
    __builtin_amdgcn_s_barrier();

    // ---- phase 3: remaining W MFMAs; tile-boundary full drain -------------
    __builtin_amdgcn_s_setprio(1);
    #pragma unroll
    for (int i = 2; i < 4; ++i)
      #pragma unroll
      for (int j = 0; j < 4; ++j)
        #pragma unroll
        for (int kk = 0; kk < 2; ++kk)
          acca[i][j] = __builtin_amdgcn_mfma_f32_16x16x32_bf16(af[i][kk], bg[j][kk], acca[i][j], 0, 0, 0);
    __builtin_amdgcn_s_setprio(0);
    __syncthreads();   // drains vmcnt+lgkmcnt: next buffer fully resident
    cur = nxt;
  }

  // fused epilogue: C/D layout col = lane&15, row = (lane>>4)*4 + reg
  #pragma unroll
  for (int j = 0; j < 4; ++j) {
    const int col = col0 + wn * 64 + j * 16 + lrow;
    const float p2 = p2v[col], pa = pav[col], an = anv[col];
    const float Bc = 1.0f - p2;
    #pragma unroll
    for (int i = 0; i < 4; ++i) {
      const int rbase = row0 + wm * 64 + i * 16 + kg * 4;
      #pragma unroll
      for (int r = 0; r < 4; ++r) {
        const int row = rbase + r;
        const float x2 = x2v[row];
        const float px = accp[i][j][r];
        const float xa = acca[i][j][r];
        const float Aq = 1.0f - 2.0f * px + x2;
        const float Dd = 1.0f - 2.0f * px + p2 * x2;
        const float inv = 1.0f / Dd;
        const float sc = (Bc * xa - Aq * pa) * inv;
        const float dnm = fabsf(Bc * (1.0f - x2) * inv) * an + 1e-15f;
        out[(size_t)row * O_DIM + col] = asinhf(2.0f * sc / dnm) * an;
      }
    }
  }
#undef STAGE_A
#undef STAGE_P
#undef STAGE_W
}

extern "C" void kernel_launch(void* const* d_in, const int* in_sizes, int n_in,
                              void* d_out, int out_size, void* d_ws, size_t ws_size,
                              hipStream_t stream) {
  (void)in_sizes; (void)n_in; (void)out_size; (void)ws_size;
  const float* x = (const float*)d_in[0];
  const float* w = (const float*)d_in[1];
  const float* b = (const float*)d_in[2];
  float* out = (float*)d_out;

  char* ws = (char*)d_ws;
  unsigned short* x_bf = (unsigned short*)ws;                               // 16 MB
  unsigned short* p_bf = (unsigned short*)(ws + (size_t)16 * 1024 * 1024);  //  8 MB
  unsigned short* a_bf = (unsigned short*)(ws + (size_t)24 * 1024 * 1024);  //  8 MB
  float* p2v = (float*)(ws + (size_t)32 * 1024 * 1024);
  float* pav = p2v + O_DIM;
  float* anv = pav + O_DIM;
  float* x2v = anv + O_DIM;

  prep_rows<<<O_DIM, 256, 0, stream>>>(w, b, a_bf, p_bf, p2v, pav, anv);
  prep_x<<<B_DIM, 256, 0, stream>>>(x, x_bf, x2v);

  hipFuncSetAttribute((const void*)hdrl_main,
                      hipFuncAttributeMaxDynamicSharedMemorySize, 131072);
  const int grid = (B_DIM / 256) * (O_DIM / 128);   // 1024
  hdrl_main<<<grid, 512, 131072, stream>>>(x_bf, p_bf, a_bf, x2v, p2v, pav, anv, out);
}

// Round 4
// 155.241 us; speedup vs baseline: 4.6269x; 1.8317x over previous
//
#include <hip/hip_runtime.h>
#include <math.h>

// ---------------------------------------------------------------------------
// HDRL Poincare MLR, c=1.
//   arg = 2*(Bc*xa - Aq*pa) / (Bc*(1-x2)*an),  Aq = 1+x2-2px, Bc = 1-p2
//   out = copysign(asinh(|arg|), arg) * an      (Dd cancels exactly; Dd>0)
// px = <x_b, p_o>, xa = <x_b, a_o> via dual bf16 MFMA GEMM (shared x tiles).
//
// R4: + T1 XCD column-stripe swizzle (B-panels L2-resident per XCD),
//     + fast epilogue (1 v_rcp, native v_log/v_sqrt asinh, Dd eliminated).
//     GEMM core unchanged from R3 (verified absmax 0.0625, 0 conflicts).
// ---------------------------------------------------------------------------

#define B_DIM 8192
#define O_DIM 4096
#define K_DIM 1024

using f32x4  = __attribute__((ext_vector_type(4))) float;
using bf16x8 = __attribute__((ext_vector_type(8))) short;

__device__ inline unsigned short f2bf(float f) {
  union { float f; unsigned u; } v; v.f = f;
  unsigned u = v.u;
  u += 0x7FFFu + ((u >> 16) & 1u);   // RNE
  return (unsigned short)(u >> 16);
}

__device__ inline void load_lds16(const void* g, void* l) {
  __builtin_amdgcn_global_load_lds(
      (const __attribute__((address_space(1))) void*)g,
      (__attribute__((address_space(3))) void*)l, 16, 0, 0);
}

__device__ inline float frcp(float x)  { float r; asm("v_rcp_f32 %0, %1"  : "=v"(r) : "v"(x)); return r; }
__device__ inline float fsqrt_(float x){ float r; asm("v_sqrt_f32 %0, %1" : "=v"(r) : "v"(x)); return r; }
__device__ inline float flog2(float x) { float r; asm("v_log_f32 %0, %1"  : "=v"(r) : "v"(x)); return r; }

// ---- per-output-row stats + bf16 conversion (weight & projected bias) -----
__global__ __launch_bounds__(256) void prep_rows(
    const float* __restrict__ wgt, const float* __restrict__ bia,
    unsigned short* __restrict__ a_bf, unsigned short* __restrict__ p_bf,
    float* __restrict__ p2v, float* __restrict__ pav, float* __restrict__ anv)
{
  const int o = blockIdx.x, t = threadIdx.x;
  const float4 w = ((const float4*)(wgt + (size_t)o * K_DIM))[t];
  const float4 b = ((const float4*)(bia + (size_t)o * K_DIM))[t];
  float a2 = w.x*w.x + w.y*w.y + w.z*w.z + w.w*w.w;
  float b2 = b.x*b.x + b.y*b.y + b.z*b.z + b.w*b.w;
  float ab = w.x*b.x + w.y*b.y + w.z*b.z + w.w*b.w;
  #pragma unroll
  for (int off = 32; off; off >>= 1) {
    a2 += __shfl_down(a2, off);
    b2 += __shfl_down(b2, off);
    ab += __shfl_down(ab, off);
  }
  __shared__ float sa[4], sb[4], sc_[4];
  const int wv = t >> 6, ln = t & 63;
  if (ln == 0) { sa[wv] = a2; sb[wv] = b2; sc_[wv] = ab; }
  __syncthreads();
  const float A2 = sa[0] + sa[1] + sa[2] + sa[3];
  const float B2 = sb[0] + sb[1] + sb[2] + sb[3];
  const float AB = sc_[0] + sc_[1] + sc_[2] + sc_[3];
  const float norm = sqrtf(B2);
  const float maxn = 1.0f - 1e-5f;            // (1-PROJ_EPS)/sqrt(c), c=1
  const float s = (norm > maxn) ? (maxn / norm) : 1.0f;
  if (t == 0) { p2v[o] = B2 * s * s; pav[o] = AB * s; anv[o] = sqrtf(A2); }
  unsigned short* ao = a_bf + (size_t)o * K_DIM + t * 4;
  unsigned short* po = p_bf + (size_t)o * K_DIM + t * 4;
  ao[0] = f2bf(w.x); ao[1] = f2bf(w.y); ao[2] = f2bf(w.z); ao[3] = f2bf(w.w);
  po[0] = f2bf(b.x * s); po[1] = f2bf(b.y * s); po[2] = f2bf(b.z * s); po[3] = f2bf(b.w * s);
}

// ---- per-batch-row stats + bf16 conversion of x ---------------------------
__global__ __launch_bounds__(256) void prep_x(
    const float* __restrict__ x, unsigned short* __restrict__ x_bf,
    float* __restrict__ x2v)
{
  const int bi = blockIdx.x, t = threadIdx.x;
  const float4 v = ((const float4*)(x + (size_t)bi * K_DIM))[t];
  float s2 = v.x*v.x + v.y*v.y + v.z*v.z + v.w*v.w;
  #pragma unroll
  for (int off = 32; off; off >>= 1) s2 += __shfl_down(s2, off);
  __shared__ float sl[4];
  const int wv = t >> 6, ln = t & 63;
  if (ln == 0) sl[wv] = s2;
  __syncthreads();
  if (t == 0) x2v[bi] = sl[0] + sl[1] + sl[2] + sl[3];
  unsigned short* xo = x_bf + (size_t)bi * K_DIM + t * 4;
  xo[0] = f2bf(v.x); xo[1] = f2bf(v.y); xo[2] = f2bf(v.z); xo[3] = f2bf(v.w);
}

// ---- main dual-GEMM + fused epilogue ---------------------------------------
// 8 waves (4M x 2N). BM=256, BN=128 (dual P/W), BK=64. 16 K-tiles.
// LDS per buffer (bf16 elems): A[256*64]=16384 @0, P[128*64]=8192 @16384,
// W[128*64]=8192 @24576; buffer stride 32768 elems; 2 buffers = 128 KB.
// XCD column-stripe: xcd = bid&7 owns nt in [xcd*4, xcd*4+4) -> B-panels
// (4 x 512 KB = 2 MB) stay L2-resident; same-mt blocks temporally adjacent.
__global__ __launch_bounds__(512, 2) void hdrl_main(
    const unsigned short* __restrict__ Xb,
    const unsigned short* __restrict__ Pb,
    const unsigned short* __restrict__ Ab,
    const float* __restrict__ x2v, const float* __restrict__ p2v,
    const float* __restrict__ pav, const float* __restrict__ anv,
    float* __restrict__ out)
{
  extern __shared__ unsigned short lds[];

  const int bid   = blockIdx.x;
  const int xcd   = bid & 7;
  const int local = bid >> 3;                 // 0..127 per XCD
  const int nt    = xcd * 4 + (local & 3);    // 4 n-columns per XCD
  const int mt    = local >> 2;               // 0..31
  const int row0 = mt * 256, col0 = nt * 128;
  const int t    = threadIdx.x;
  const int wv   = t >> 6, lane = t & 63;
  const int wm   = wv >> 1, wn = wv & 1;      // 4M x 2N waves
  const int lrow = lane & 15, kg = lane >> 4;
  const int sw   = (lrow & 7) << 3;           // read-side XOR key (elems)

  // staging: thread t covers chunk (r = q*64 + (t>>3), c = t&7), 16B chunks
  const int sr   = t >> 3;                    // 0..63
  const int sc   = t & 7;
  const int scol = (sc ^ (sr & 7)) * 8;       // inverse-swizzled source col
  const unsigned short* gA = Xb + (size_t)(row0 + sr) * K_DIM + scol;
  const unsigned short* gP = Pb + (size_t)(col0 + sr) * K_DIM + scol;
  const unsigned short* gW = Ab + (size_t)(col0 + sr) * K_DIM + scol;

  f32x4 accp[4][4], acca[4][4];
  #pragma unroll
  for (int i = 0; i < 4; ++i)
    #pragma unroll
    for (int j = 0; j < 4; ++j) { accp[i][j] = (f32x4)0.0f; acca[i][j] = (f32x4)0.0f; }

#define STAGE_A(q) load_lds16(gA + (size_t)(q)*64*K_DIM + k0n, (void*)&lds[nb + (q)*4096 + wv*512])
#define STAGE_P(q) load_lds16(gP + (size_t)(q)*64*K_DIM + k0n, (void*)&lds[nb + 16384 + (q)*4096 + wv*512])
#define STAGE_W(q) load_lds16(gW + (size_t)(q)*64*K_DIM + k0n, (void*)&lds[nb + 24576 + (q)*4096 + wv*512])

  // prologue: stage tile 0 into buffer 0
  {
    const int nb = 0, k0n = 0;
    STAGE_A(0); STAGE_A(1); STAGE_A(2); STAGE_A(3);
    STAGE_P(0); STAGE_P(1); STAGE_W(0); STAGE_W(1);
  }
  __syncthreads();

  int cur = 0;
  for (int kt = 0; kt < 16; ++kt) {
    const int nxt = cur ^ 1;
    const int nb  = nxt * 32768;
    const int cb  = cur * 32768;
    const int k0n = (kt + 1) * 64;
    const bool pfn = (kt < 15);

    bf16x8 af[4][2], bg[4][2];
    const int kbs0 = (kg * 8) ^ sw;
    const int kbs1 = (32 + kg * 8) ^ sw;

    // ---- phase 0: read af[0..1], all P frags; stage A0,A1,P0 --------------
    #pragma unroll
    for (int i = 0; i < 2; ++i) {
      af[i][0] = *(const bf16x8*)&lds[cb + (wm*64 + i*16 + lrow)*64 + kbs0];
      af[i][1] = *(const bf16x8*)&lds[cb + (wm*64 + i*16 + lrow)*64 + kbs1];
    }
    #pragma unroll
    for (int j = 0; j < 4; ++j) {
      bg[j][0] = *(const bf16x8*)&lds[cb + 16384 + (wn*64 + j*16 + lrow)*64 + kbs0];
      bg[j][1] = *(const bf16x8*)&lds[cb + 16384 + (wn*64 + j*16 + lrow)*64 + kbs1];
    }
    if (pfn) { STAGE_A(0); STAGE_A(1); STAGE_P(0); }
    __builtin_amdgcn_s_barrier();
    asm volatile("s_waitcnt lgkmcnt(0)" ::: "memory");
    __builtin_amdgcn_s_setprio(1);
    #pragma unroll
    for (int i = 0; i < 2; ++i)
      #pragma unroll
      for (int j = 0; j < 4; ++j)
        #pragma unroll
        for (int kk = 0; kk < 2; ++kk)
          accp[i][j] = __builtin_amdgcn_mfma_f32_16x16x32_bf16(af[i][kk], bg[j][kk], accp[i][j], 0, 0, 0);
    __builtin_amdgcn_s_setprio(0);
    __builtin_amdgcn_s_barrier();

    // ---- phase 1: read af[2..3]; stage A2,A3,P1 ---------------------------
    #pragma unroll
    for (int i = 2; i < 4; ++i) {
      af[i][0] = *(const bf16x8*)&lds[cb + (wm*64 + i*16 + lrow)*64 + kbs0];
      af[i][1] = *(const bf16x8*)&lds[cb + (wm*64 + i*16 + lrow)*64 + kbs1];
    }
    if (pfn) { STAGE_A(2); STAGE_A(3); STAGE_P(1); }
    __builtin_amdgcn_s_barrier();
    asm volatile("s_waitcnt lgkmcnt(0)" ::: "memory");
    __builtin_amdgcn_s_setprio(1);
    #pragma unroll
    for (int i = 2; i < 4; ++i)
      #pragma unroll
      for (int j = 0; j < 4; ++j)
        #pragma unroll
        for (int kk = 0; kk < 2; ++kk)
          accp[i][j] = __builtin_amdgcn_mfma_f32_16x16x32_bf16(af[i][kk], bg[j][kk], accp[i][j], 0, 0, 0);
    __builtin_amdgcn_s_setprio(0);
    __builtin_amdgcn_s_barrier();

    // ---- phase 2: read all W frags (reuse bg); stage W0,W1 ----------------
    #pragma unroll
    for (int j = 0; j < 4; ++j) {
      bg[j][0] = *(const bf16x8*)&lds[cb + 24576 + (wn*64 + j*16 + lrow)*64 + kbs0];
      bg[j][1] = *(const bf16x8*)&lds[cb + 24576 + (wn*64 + j*16 + lrow)*64 + kbs1];
    }
    if (pfn) { STAGE_W(0); STAGE_W(1); }
    __builtin_amdgcn_s_barrier();
    asm volatile("s_waitcnt lgkmcnt(0)" ::: "memory");
    __builtin_amdgcn_s_setprio(1);
    #pragma unroll
    for (int i = 0; i < 2; ++i)
      #pragma unroll
      for (int j = 0; j < 4; ++j)
        #pragma unroll
        for (int kk = 0; kk < 2; ++kk)
          acca[i][j] = __builtin_amdgcn_mfma_f32_16x16x32_bf16(af[i][kk], bg[j][kk], acca[i][j], 0, 0, 0);
    __builtin_amdgcn_s_setprio(0);
    __builtin_amdgcn_s_barrier();

    // ---- phase 3: remaining W MFMAs; tile-boundary full drain -------------
    __builtin_amdgcn_s_setprio(1);
    #pragma unroll
    for (int i = 2; i < 4; ++i)
      #pragma unroll
      for (int j = 0; j < 4; ++j)
        #pragma unroll
        for (int kk = 0; kk < 2; ++kk)
          acca[i][j] = __builtin_amdgcn_mfma_f32_16x16x32_bf16(af[i][kk], bg[j][kk], acca[i][j], 0, 0, 0);
    __builtin_amdgcn_s_setprio(0);
    __syncthreads();   // drains vmcnt+lgkmcnt: next buffer fully resident
    cur = nxt;
  }

  // fused epilogue: C/D layout col = lane&15, row = (lane>>4)*4 + reg.
  // arg = 2*(Bc*xa - Aq*pa) / (Bc*(1-x2)*an); out = copysign(asinh|arg|,arg)*an
  #pragma unroll
  for (int j = 0; j < 4; ++j) {
    const int col = col0 + wn * 64 + j * 16 + lrow;
    const float Bc = 1.0f - p2v[col];
    const float pa = pav[col];
    const float an = anv[col];
    const float dja = Bc * an;                 // denom col factor
    const float lc  = 0.69314718f * an;        // ln2 * a_norm
    #pragma unroll
    for (int i = 0; i < 4; ++i) {
      const int rbase = row0 + wm * 64 + i * 16 + kg * 4;
      #pragma unroll
      for (int r = 0; r < 4; ++r) {
        const int row = rbase + r;
        const float x2 = x2v[row];
        const float px = accp[i][j][r];
        const float xa = acca[i][j][r];
        const float Aq = (1.0f + x2) - 2.0f * px;
        const float numer = Bc * xa - Aq * pa;
        const float denom = dja * (1.0f - x2) + 1e-15f;
        const float arg = 2.0f * numer * frcp(denom);
        const float aa  = fabsf(arg);
        const float u   = aa + fsqrt_(__builtin_fmaf(aa, aa, 1.0f));
        out[(size_t)row * O_DIM + col] = copysignf(flog2(u) * lc, arg);
      }
    }
  }
#undef STAGE_A
#undef STAGE_P
#undef STAGE_W
}

extern "C" void kernel_launch(void* const* d_in, const int* in_sizes, int n_in,
                              void* d_out, int out_size, void* d_ws, size_t ws_size,
                              hipStream_t stream) {
  (void)in_sizes; (void)n_in; (void)out_size; (void)ws_size;
  const float* x = (const float*)d_in[0];
  const float* w = (const float*)d_in[1];
  const float* b = (const float*)d_in[2];
  float* out = (float*)d_out;

  char* ws = (char*)d_ws;
  unsigned short* x_bf = (unsigned short*)ws;                               // 16 MB
  unsigned short* p_bf = (unsigned short*)(ws + (size_t)16 * 1024 * 1024);  //  8 MB
  unsigned short* a_bf = (unsigned short*)(ws + (size_t)24 * 1024 * 1024);  //  8 MB
  float* p2v = (float*)(ws + (size_t)32 * 1024 * 1024);
  float* pav = p2v + O_DIM;
  float* anv = pav + O_DIM;
  float* x2v = anv + O_DIM;

  prep_rows<<<O_DIM, 256, 0, stream>>>(w, b, a_bf, p_bf, p2v, pav, anv);
  prep_x<<<B_DIM, 256, 0, stream>>>(x, x_bf, x2v);

  hipFuncSetAttribute((const void*)hdrl_main,
                      hipFuncAttributeMaxDynamicSharedMemorySize, 131072);
  const int grid = (B_DIM / 256) * (O_DIM / 128);   // 1024
  hdrl_main<<<grid, 512, 131072, stream>>>(x_bf, p_bf, a_bf, x2v, p2v, pav, anv, out);
}

// Round 5
// 150.056 us; speedup vs baseline: 4.7868x; 1.0346x over previous
//
#include <hip/hip_runtime.h>
#include <math.h>

// ---------------------------------------------------------------------------
// HDRL Poincare MLR, c=1.
//   arg = 2*(Bc*xa - Aq*pa) / (Bc*(1-x2)*an),  Aq = 1+x2-2px, Bc = 1-p2
//   out = copysign(asinh(|arg|), arg) * an      (Dd cancels exactly; Dd>0)
// px = <x_b, p_o>, xa = <x_b, a_o> via dual bf16 MFMA GEMM (shared x tiles).
//
// R5: ONE barrier per K-tile (dbuf makes mid-tile barriers unnecessary);
//     compiler interleaves ds_read<->MFMA (m97-style fine lgkmcnt) so LDS
//     time hides under MFMA time instead of serializing with it.
//     Keeps: XCD column-stripe (R4), XOR swizzle (R2), fast epilogue (R4).
// ---------------------------------------------------------------------------

#define B_DIM 8192
#define O_DIM 4096
#define K_DIM 1024

using f32x4  = __attribute__((ext_vector_type(4))) float;
using bf16x8 = __attribute__((ext_vector_type(8))) short;

__device__ inline unsigned short f2bf(float f) {
  union { float f; unsigned u; } v; v.f = f;
  unsigned u = v.u;
  u += 0x7FFFu + ((u >> 16) & 1u);   // RNE
  return (unsigned short)(u >> 16);
}

__device__ inline void load_lds16(const void* g, void* l) {
  __builtin_amdgcn_global_load_lds(
      (const __attribute__((address_space(1))) void*)g,
      (__attribute__((address_space(3))) void*)l, 16, 0, 0);
}

__device__ inline float frcp(float x)  { float r; asm("v_rcp_f32 %0, %1"  : "=v"(r) : "v"(x)); return r; }
__device__ inline float fsqrt_(float x){ float r; asm("v_sqrt_f32 %0, %1" : "=v"(r) : "v"(x)); return r; }
__device__ inline float flog2(float x) { float r; asm("v_log_f32 %0, %1"  : "=v"(r) : "v"(x)); return r; }

// ---- per-output-row stats + bf16 conversion (weight & projected bias) -----
__global__ __launch_bounds__(256) void prep_rows(
    const float* __restrict__ wgt, const float* __restrict__ bia,
    unsigned short* __restrict__ a_bf, unsigned short* __restrict__ p_bf,
    float* __restrict__ p2v, float* __restrict__ pav, float* __restrict__ anv)
{
  const int o = blockIdx.x, t = threadIdx.x;
  const float4 w = ((const float4*)(wgt + (size_t)o * K_DIM))[t];
  const float4 b = ((const float4*)(bia + (size_t)o * K_DIM))[t];
  float a2 = w.x*w.x + w.y*w.y + w.z*w.z + w.w*w.w;
  float b2 = b.x*b.x + b.y*b.y + b.z*b.z + b.w*b.w;
  float ab = w.x*b.x + w.y*b.y + w.z*b.z + w.w*b.w;
  #pragma unroll
  for (int off = 32; off; off >>= 1) {
    a2 += __shfl_down(a2, off);
    b2 += __shfl_down(b2, off);
    ab += __shfl_down(ab, off);
  }
  __shared__ float sa[4], sb[4], sc_[4];
  const int wv = t >> 6, ln = t & 63;
  if (ln == 0) { sa[wv] = a2; sb[wv] = b2; sc_[wv] = ab; }
  __syncthreads();
  const float A2 = sa[0] + sa[1] + sa[2] + sa[3];
  const float B2 = sb[0] + sb[1] + sb[2] + sb[3];
  const float AB = sc_[0] + sc_[1] + sc_[2] + sc_[3];
  const float norm = sqrtf(B2);
  const float maxn = 1.0f - 1e-5f;            // (1-PROJ_EPS)/sqrt(c), c=1
  const float s = (norm > maxn) ? (maxn / norm) : 1.0f;
  if (t == 0) { p2v[o] = B2 * s * s; pav[o] = AB * s; anv[o] = sqrtf(A2); }
  unsigned short* ao = a_bf + (size_t)o * K_DIM + t * 4;
  unsigned short* po = p_bf + (size_t)o * K_DIM + t * 4;
  ao[0] = f2bf(w.x); ao[1] = f2bf(w.y); ao[2] = f2bf(w.z); ao[3] = f2bf(w.w);
  po[0] = f2bf(b.x * s); po[1] = f2bf(b.y * s); po[2] = f2bf(b.z * s); po[3] = f2bf(b.w * s);
}

// ---- per-batch-row stats + bf16 conversion of x ---------------------------
__global__ __launch_bounds__(256) void prep_x(
    const float* __restrict__ x, unsigned short* __restrict__ x_bf,
    float* __restrict__ x2v)
{
  const int bi = blockIdx.x, t = threadIdx.x;
  const float4 v = ((const float4*)(x + (size_t)bi * K_DIM))[t];
  float s2 = v.x*v.x + v.y*v.y + v.z*v.z + v.w*v.w;
  #pragma unroll
  for (int off = 32; off; off >>= 1) s2 += __shfl_down(s2, off);
  __shared__ float sl[4];
  const int wv = t >> 6, ln = t & 63;
  if (ln == 0) sl[wv] = s2;
  __syncthreads();
  if (t == 0) x2v[bi] = sl[0] + sl[1] + sl[2] + sl[3];
  unsigned short* xo = x_bf + (size_t)bi * K_DIM + t * 4;
  xo[0] = f2bf(v.x); xo[1] = f2bf(v.y); xo[2] = f2bf(v.z); xo[3] = f2bf(v.w);
}

// ---- main dual-GEMM + fused epilogue ---------------------------------------
// 8 waves (4M x 2N). BM=256, BN=128 (dual P/W), BK=64. 16 K-tiles.
// LDS per buffer (bf16 elems): A[256*64]=16384 @0, P[128*64]=8192 @16384,
// W[128*64]=8192 @24576; buffer stride 32768 elems; 2 buffers = 128 KB.
// XCD column-stripe: xcd = bid&7 owns nt in [xcd*4, xcd*4+4).
// One __syncthreads per K-tile: stage(t+1)->nxt while computing cur is
// race-free; the sync drains vmcnt (stage resident) + lgkm and flips buffers.
__global__ __launch_bounds__(512, 2) void hdrl_main(
    const unsigned short* __restrict__ Xb,
    const unsigned short* __restrict__ Pb,
    const unsigned short* __restrict__ Ab,
    const float* __restrict__ x2v, const float* __restrict__ p2v,
    const float* __restrict__ pav, const float* __restrict__ anv,
    float* __restrict__ out)
{
  extern __shared__ unsigned short lds[];

  const int bid   = blockIdx.x;
  const int xcd   = bid & 7;
  const int local = bid >> 3;                 // 0..127 per XCD
  const int nt    = xcd * 4 + (local & 3);    // 4 n-columns per XCD
  const int mt    = local >> 2;               // 0..31
  const int row0 = mt * 256, col0 = nt * 128;
  const int t    = threadIdx.x;
  const int wv   = t >> 6, lane = t & 63;
  const int wm   = wv >> 1, wn = wv & 1;      // 4M x 2N waves
  const int lrow = lane & 15, kg = lane >> 4;
  const int sw   = (lrow & 7) << 3;           // read-side XOR key (elems)

  // staging: thread t covers chunk (r = q*64 + (t>>3), c = t&7), 16B chunks
  const int sr   = t >> 3;                    // 0..63
  const int sc   = t & 7;
  const int scol = (sc ^ (sr & 7)) * 8;       // inverse-swizzled source col
  const unsigned short* gA = Xb + (size_t)(row0 + sr) * K_DIM + scol;
  const unsigned short* gP = Pb + (size_t)(col0 + sr) * K_DIM + scol;
  const unsigned short* gW = Ab + (size_t)(col0 + sr) * K_DIM + scol;

  f32x4 accp[4][4], acca[4][4];
  #pragma unroll
  for (int i = 0; i < 4; ++i)
    #pragma unroll
    for (int j = 0; j < 4; ++j) { accp[i][j] = (f32x4)0.0f; acca[i][j] = (f32x4)0.0f; }

#define STAGE_A(q) load_lds16(gA + (size_t)(q)*64*K_DIM + k0n, (void*)&lds[nb + (q)*4096 + wv*512])
#define STAGE_P(q) load_lds16(gP + (size_t)(q)*64*K_DIM + k0n, (void*)&lds[nb + 16384 + (q)*4096 + wv*512])
#define STAGE_W(q) load_lds16(gW + (size_t)(q)*64*K_DIM + k0n, (void*)&lds[nb + 24576 + (q)*4096 + wv*512])

  // prologue: stage tile 0 into buffer 0
  {
    const int nb = 0, k0n = 0;
    STAGE_A(0); STAGE_A(1); STAGE_A(2); STAGE_A(3);
    STAGE_P(0); STAGE_P(1); STAGE_W(0); STAGE_W(1);
  }
  __syncthreads();

  int cur = 0;
  for (int kt = 0; kt < 16; ++kt) {
    const int nxt = cur ^ 1;
    const int nb  = nxt * 32768;
    const int cb  = cur * 32768;
    const int k0n = (kt + 1) * 64;

    // stage next tile first: loads get the whole compute phase to land
    if (kt < 15) {
      STAGE_A(0); STAGE_A(1); STAGE_A(2); STAGE_A(3);
      STAGE_P(0); STAGE_P(1); STAGE_W(0); STAGE_W(1);
    }

    const int kbs0 = (kg * 8) ^ sw;
    const int kbs1 = (32 + kg * 8) ^ sw;
    bf16x8 af[4][2], bp[4][2], bw[4][2];
    #pragma unroll
    for (int i = 0; i < 4; ++i) {
      af[i][0] = *(const bf16x8*)&lds[cb + (wm*64 + i*16 + lrow)*64 + kbs0];
      af[i][1] = *(const bf16x8*)&lds[cb + (wm*64 + i*16 + lrow)*64 + kbs1];
    }
    #pragma unroll
    for (int j = 0; j < 4; ++j) {
      bp[j][0] = *(const bf16x8*)&lds[cb + 16384 + (wn*64 + j*16 + lrow)*64 + kbs0];
      bp[j][1] = *(const bf16x8*)&lds[cb + 16384 + (wn*64 + j*16 + lrow)*64 + kbs1];
    }
    #pragma unroll
    for (int j = 0; j < 4; ++j) {
      bw[j][0] = *(const bf16x8*)&lds[cb + 24576 + (wn*64 + j*16 + lrow)*64 + kbs0];
      bw[j][1] = *(const bf16x8*)&lds[cb + 24576 + (wn*64 + j*16 + lrow)*64 + kbs1];
    }

    // no mid-tile barriers: compiler interleaves ds_read waits with MFMAs
    __builtin_amdgcn_s_setprio(1);
    #pragma unroll
    for (int i = 0; i < 4; ++i)
      #pragma unroll
      for (int j = 0; j < 4; ++j)
        #pragma unroll
        for (int kk = 0; kk < 2; ++kk)
          accp[i][j] = __builtin_amdgcn_mfma_f32_16x16x32_bf16(af[i][kk], bp[j][kk], accp[i][j], 0, 0, 0);
    #pragma unroll
    for (int i = 0; i < 4; ++i)
      #pragma unroll
      for (int j = 0; j < 4; ++j)
        #pragma unroll
        for (int kk = 0; kk < 2; ++kk)
          acca[i][j] = __builtin_amdgcn_mfma_f32_16x16x32_bf16(af[i][kk], bw[j][kk], acca[i][j], 0, 0, 0);
    __builtin_amdgcn_s_setprio(0);

    __syncthreads();   // drains vmcnt+lgkmcnt: next buffer fully resident
    cur = nxt;
  }

  // fused epilogue: C/D layout col = lane&15, row = (lane>>4)*4 + reg.
  // arg = 2*(Bc*xa - Aq*pa) / (Bc*(1-x2)*an); out = copysign(asinh|arg|,arg)*an
  // j innermost for stores: each wave's 4 j-stores form 256 B contiguous.
  float Bcj[4], paj[4], dja[4], lcj[4];
  #pragma unroll
  for (int j = 0; j < 4; ++j) {
    const int col = col0 + wn * 64 + j * 16 + lrow;
    const float Bc = 1.0f - p2v[col];
    const float an = anv[col];
    Bcj[j] = Bc; paj[j] = pav[col];
    dja[j] = Bc * an;                 // denom col factor
    lcj[j] = 0.69314718f * an;        // ln2 * a_norm
  }
  #pragma unroll
  for (int i = 0; i < 4; ++i) {
    const int rbase = row0 + wm * 64 + i * 16 + kg * 4;
    #pragma unroll
    for (int r = 0; r < 4; ++r) {
      const int row = rbase + r;
      const float x2 = x2v[row];
      const float Aqh = 1.0f + x2;
      const float omx = 1.0f - x2;
      float* orow = out + (size_t)row * O_DIM + col0 + wn * 64 + lrow;
      #pragma unroll
      for (int j = 0; j < 4; ++j) {
        const float px = accp[i][j][r];
        const float xa = acca[i][j][r];
        const float numer = Bcj[j] * xa - (Aqh - 2.0f * px) * paj[j];
        const float denom = dja[j] * omx + 1e-15f;
        const float arg = 2.0f * numer * frcp(denom);
        const float aa  = fabsf(arg);
        const float u   = aa + fsqrt_(__builtin_fmaf(aa, aa, 1.0f));
        orow[j * 16] = copysignf(flog2(u) * lcj[j], arg);
      }
    }
  }
#undef STAGE_A
#undef STAGE_P
#undef STAGE_W
}

extern "C" void kernel_launch(void* const* d_in, const int* in_sizes, int n_in,
                              void* d_out, int out_size, void* d_ws, size_t ws_size,
                              hipStream_t stream) {
  (void)in_sizes; (void)n_in; (void)out_size; (void)ws_size;
  const float* x = (const float*)d_in[0];
  const float* w = (const float*)d_in[1];
  const float* b = (const float*)d_in[2];
  float* out = (float*)d_out;

  char* ws = (char*)d_ws;
  unsigned short* x_bf = (unsigned short*)ws;                               // 16 MB
  unsigned short* p_bf = (unsigned short*)(ws + (size_t)16 * 1024 * 1024);  //  8 MB
  unsigned short* a_bf = (unsigned short*)(ws + (size_t)24 * 1024 * 1024);  //  8 MB
  float* p2v = (float*)(ws + (size_t)32 * 1024 * 1024);
  float* pav = p2v + O_DIM;
  float* anv = pav + O_DIM;
  float* x2v = anv + O_DIM;

  prep_rows<<<O_DIM, 256, 0, stream>>>(w, b, a_bf, p_bf, p2v, pav, anv);
  prep_x<<<B_DIM, 256, 0, stream>>>(x, x_bf, x2v);

  hipFuncSetAttribute((const void*)hdrl_main,
                      hipFuncAttributeMaxDynamicSharedMemorySize, 131072);
  const int grid = (B_DIM / 256) * (O_DIM / 128);   // 1024
  hdrl_main<<<grid, 512, 131072, stream>>>(x_bf, p_bf, a_bf, x2v, p2v, pav, anv, out);
}